// Round 6
// baseline (4627.683 us; speedup 1.0000x reference)
//
#include <hip/hip_runtime.h>
#include <math.h>

#define BB 512
#define HH 512
#define FF 72
#define NCC 10
#define EE 64
#define TTRAJ 120
#define TOUT 120
#define INWW 713
#define GG 2048
#define WSZE ((size_t)GG*1024)    // elements per converted weight matrix
#define BH  ((size_t)BB*HH)       // elements per activation buffer

typedef _Float16 f16x8 __attribute__((ext_vector_type(8)));
typedef float f32x4 __attribute__((ext_vector_type(4)));
typedef int i32x4 __attribute__((ext_vector_type(4)));

__device__ __forceinline__ float sigmoidf_(float x){ return 1.0f/(1.0f+__expf(-x)); }
// fast tanh via __expf: max abs err ~1e-7 vs libm, far below fp16 output quantum.
// Saturates correctly: e->inf => 1, e->0 => -1.
__device__ __forceinline__ float tanhf_(float x){
    float e = __expf(2.0f*x);
    return 1.0f - 2.0f/(e + 1.0f);
}

// sc0 (L1-bypass) 16B load via raw buffer intrinsic (validated r5/r7): reads
// the XCD L2 directly where same-XCD producers' dirty activation lines live.
extern "C" __device__ f32x4 llvm_amdgcn_raw_buffer_load_v4f32(
    i32x4 rsrc, int voffset, int soffset, int cpol) __asm("llvm.amdgcn.raw.buffer.load.v4f32");

__device__ __forceinline__ i32x4 make_srd(const void* p){
    union { const void* p; unsigned long long u; } a; a.p = p;
    i32x4 r;
    r.x = (int)(a.u & 0xFFFFFFFFull);
    r.y = (int)(a.u >> 32);          // stride=0, base hi bits
    r.z = -1;                        // num_records = 0xFFFFFFFF (bounds off)
    r.w = 0x00020000;                // raw dword access
    return r;
}

__device__ __forceinline__ f16x8 ldA(i32x4 srd, int voff){
    f32x4 v = llvm_amdgcn_raw_buffer_load_v4f32(srd, voff, 0, 1);  // sc0
    union { f32x4 f; f16x8 h; } u; u.f = v; return u.h;
}

// Build fp16 Wcat[g*512+j][0:512]=Wih, [512:1024]=Whh
__global__ void conv_wcat_kernel(const float* __restrict__ ih,
                                 const float* __restrict__ hh,
                                 _Float16* __restrict__ dst)
{
    int idx = blockIdx.x*256 + threadIdx.x;   // 2048*256 quads
    int j  = idx >> 8;
    int k4 = (idx & 255) * 4;
    const float* src = (k4 < 512) ? (ih + (size_t)j*512 + k4)
                                  : (hh + (size_t)j*512 + (k4-512));
    float4 v = *(const float4*)src;
    _Float16* d = dst + (size_t)j*1024 + k4;
    d[0] = (_Float16)v.x; d[1] = (_Float16)v.y;
    d[2] = (_Float16)v.z; d[3] = (_Float16)v.w;
}

// cond_out[b*H+j] = emb_b[j] + sum_i (label outer cemb)[b,i]*emb_W[j][72+i]
__global__ void cond_kernel(const float* __restrict__ label,
                            const float* __restrict__ cemb,
                            const float* __restrict__ embW,
                            const float* __restrict__ embB,
                            float* __restrict__ cond_out)
{
    __shared__ float sl[NCC];
    __shared__ float se[EE];
    __shared__ float sc[NCC*EE];
    int b = blockIdx.x;
    int tid = threadIdx.x;
    if (tid < NCC) sl[tid] = label[b*NCC + tid];
    else if (tid >= 32 && tid < 32+EE) se[tid-32] = cemb[b*EE + (tid-32)];
    __syncthreads();
    for (int i = tid; i < NCC*EE; i += 256) sc[i] = sl[i>>6]*se[i&63];
    __syncthreads();
    for (int j = tid; j < HH; j += 256){
        const float* w = embW + (size_t)j*INWW + FF;
        float acc = embB[j];
        #pragma unroll 8
        for (int i = 0; i < NCC*EE; ++i) acc += sc[i]*w[i];
        cond_out[b*HH + j] = acc;
    }
}

// Mf[j][k] = sum_f embW[j][f]*outW[f][k]   (fp16 out)
__global__ void mf_kernel(const float* __restrict__ embW,
                          const float* __restrict__ outW,
                          _Float16* __restrict__ Mf)
{
    int idx = blockIdx.x*256 + threadIdx.x;   // 512*512
    int j = idx >> 9, k = idx & 511;
    const float* ew = embW + (size_t)j*INWW;
    float acc = 0.f;
    #pragma unroll 8
    for (int f = 0; f < FF; ++f) acc += ew[f] * outW[f*512 + k];
    Mf[idx] = (_Float16)acc;
}

// biasC[4][2048], w712[512], constj[512], outWf[80][512] (fp16, zero-padded)
__global__ void prep_kernel(const float* __restrict__ encbih, const float* __restrict__ encbhh,
                            const float* __restrict__ decbih, const float* __restrict__ decbhh,
                            const float* __restrict__ embW, const float* __restrict__ outW,
                            const float* __restrict__ outB,
                            float* __restrict__ biasC, float* __restrict__ w712,
                            float* __restrict__ constj, _Float16* __restrict__ outWf)
{
    int i = blockIdx.x*256 + threadIdx.x;
    if (i < 8192){
        int l = i >> 11, g = i & 2047;
        biasC[i] = (l < 2) ? encbih[l*GG+g] + encbhh[l*GG+g]
                           : decbih[(l-2)*GG+g] + decbhh[(l-2)*GG+g];
    } else if (i < 8704){
        int j = i - 8192;
        w712[j] = embW[(size_t)j*INWW + (INWW-1)];
    } else if (i < 9216){
        int j = i - 8704;
        float acc = 0.f;
        #pragma unroll 8
        for (int f = 0; f < FF; ++f) acc += embW[(size_t)j*INWW + f] * outB[f];
        constj[j] = acc;
    } else if (i < 9216 + 80*512){
        int ii = i - 9216;
        int f = ii >> 9, k = ii & 511;
        outWf[ii] = (f < FF) ? (_Float16)outW[f*512 + k] : (_Float16)0.f;
    }
}

// ---------------- persistent kernel (normal launch + flag group barriers) ----
// 256 blocks x 256 threads, 1 block/CU. rt = bid&7 (XCD-local group of 32 blocks),
// jt = bid>>3. Block owns rows rt*64..+63, h-cols jt*16..+15. Wave w = gate w.
__global__ __launch_bounds__(256, 1)
void persistent_kernel(const _Float16* __restrict__ wcat, const float* __restrict__ biasC,
                       const float* __restrict__ traj, const float* __restrict__ encW,
                       const float* __restrict__ encB, const float* __restrict__ prelu_a,
                       _Float16* __restrict__ xping, _Float16* __restrict__ h0p,
                       _Float16* __restrict__ h1p, _Float16* __restrict__ xdec,
                       const float* __restrict__ cond, const _Float16* __restrict__ Mf,
                       const float* __restrict__ w712, const float* __restrict__ constj,
                       const _Float16* __restrict__ outWf, const float* __restrict__ outB,
                       float* __restrict__ dout, unsigned* __restrict__ bar)
{
    // smem layout:
    //   [0      ..  65536)  buf0[64][512] fp16 — FRESH A-half, XOR-swizzled:
    //                       buf[row][y] = A[row][y ^ ((row&7)<<4)]
    //   [65536  .. 131072)  buf1[64][512] fp16 — AVAIL A-half (recurrent h)
    //   [131072 .. 148480)  gx[4][64][17]  f32  (also out_step partial buffer)
    //   [148480 .. 157184)  cst[2][64][17] f32 — persistent cell state
    __shared__ __align__(16) char smem[157184];
    char* buf0 = smem;
    char* buf1 = smem + 65536;
    float (*gx)[64][17]  = (float (*)[64][17])(smem + 131072);
    float (*cst)[64][17] = (float (*)[64][17])(smem + 148480);

    const int tid = threadIdx.x;
    const int w    = tid >> 6;       // gate / weight-group
    const int lane = tid & 63;
    const int m    = lane & 15;
    const int q    = lane >> 4;
    const int bid  = blockIdx.x;
    const int rt   = bid & 7;        // group id (XCD-local under %8 round-robin)
    const int jt   = bid >> 3;       // 0..31
    const int r0   = rt * 64;
    const int j0   = jt * 16;
    const float pa = prelu_a[0];
    unsigned* fl = bar + rt*32*32;   // 32 flags, 128B apart (PROVEN layout, R4)
    unsigned seq = 0;

    // Round-7 barrier protocol, verbatim (monotone seq, volatile store, wave-0
    // volatile poll, no fences/RMW, 128B-apart flags). Split begin/end so
    // stale-data staging can overlap the wait window (proven R4).
    auto gbar_begin = [&](){
        ++seq;
        __syncthreads();
        if (tid == 0)
            *(volatile unsigned*)(fl + jt*32) = seq;
    };
    auto gbar_end = [&](){
        if (tid < 64){
            long long t0 = clock64();
            for(;;){
                unsigned v = (tid < 32) ? *(volatile unsigned*)(fl + tid*32) : seq;
                if (__ballot((int)(seq - v) > 0) == 0ULL) break;
                __builtin_amdgcn_s_sleep(1);
                if (clock64() - t0 > 40000000LL) break;   // bail: wrong answer beats hang
            }
        }
        __syncthreads();
    };
    auto gbar = [&](){ gbar_begin(); gbar_end(); };

    for (int i = tid; i < 2*64*17; i += 256) ((float*)(smem + 148480))[i] = 0.f;

    f16x8 WB0[32], WB1[32];
    auto load_wb = [&](const _Float16* base0, const _Float16* base1){
        const _Float16* p0 = base0 + ((size_t)(w*512 + j0 + m))*1024 + q*8;
        const _Float16* p1 = base1 + ((size_t)(w*512 + j0 + m))*1024 + q*8;
        #pragma unroll
        for (int kc = 0; kc < 32; ++kc){
            WB0[kc] = *(const f16x8*)(p0 + kc*32);
            WB1[kc] = *(const f16x8*)(p1 + kc*32);
        }
    };

    // wave w owns rows {(g*8+i)*4+w}; per row, lanes read 1KB contiguous (sc0,
    // coalesced) and write 1KB to one LDS row (wave-uniform row, swizzled cols).
    auto stage_rows8 = [&](i32x4 s, int g, f16x8* v){
        #pragma unroll
        for (int i = 0; i < 8; ++i)
            v[i] = ldA(s, (r0 + (g*8 + i)*4 + w)*1024 + lane*16);
    };
    auto write_rows8 = [&](char* buf, int g, f16x8* v){
        #pragma unroll
        for (int i = 0; i < 8; ++i){
            const int row = (g*8 + i)*4 + w;
            *(f16x8*)(buf + row*1024 + ((lane*16) ^ ((row&7)<<4))) = v[i];
        }
    };
    // stage the avail (recurrent) half into buf1: used inside barrier windows /
    // emb segments; completion guaranteed by the next __syncthreads.
    auto stage_avail = [&](const _Float16* A){
        i32x4 s = make_srd(A);
        f16x8 va[8], vb[8];
        stage_rows8(s, 0, va);
        stage_rows8(s, 1, vb);
        write_rows8(buf1, 0, va);
        write_rows8(buf1, 1, vb);
    };

    // per-thread swizzled base: row m, col bytes q*16, XOR (m&7)<<4.
    // kc*64 folds via XOR (disjoint bits within the 1024B row); rf*16384
    // adds 16 rows (row&7 invariant -> same swizzle).
    const int at = m*1024 + ((q*16) ^ ((m&7)<<4));

    auto khalf = [&](const char* ab, const f16x8* WBh, int c0, int c1, f32x4* acc){
        #pragma unroll
        for (int kc = c0; kc < c1; ++kc){
            const int ko = at ^ (kc*64);
            #pragma unroll
            for (int rf = 0; rf < 4; ++rf){
                f16x8 av = *(const f16x8*)(ab + (ko + rf*16384));
                acc[rf] = __builtin_amdgcn_mfma_f32_16x16x32_f16(av, WBh[kc], acc[rf], 0,0,0);
            }
        }
    };

    auto elementwise = [&](f32x4* acc, _Float16* dst, int cidx){
        #pragma unroll
        for (int rf = 0; rf < 4; ++rf)
            #pragma unroll
            for (int r = 0; r < 4; ++r)
                gx[w][rf*16 + q*4 + r][m] = acc[rf][r];
        __syncthreads();
        #pragma unroll
        for (int r = 0; r < 4; ++r){
            int row = w*16 + q*4 + r;
            float ig = sigmoidf_(gx[0][row][m]);
            float fg = sigmoidf_(gx[1][row][m]);
            float gv = tanhf_(gx[2][row][m]);
            float og = sigmoidf_(gx[3][row][m]);
            float cp = cst[cidx][row][m];
            float cn = fg*cp + ig*gv;
            cst[cidx][row][m] = cn;
            dst[((size_t)(r0 + row))*512 + j0 + m] = (_Float16)(og*tanhf_(cn));
        }
    };

    // decoder form: buf1 already holds the avail half (staged in a barrier
    // window). Fresh-half loads are interleaved with avail-half MFMAs.
    auto layer_step_dec = [&](const f16x8* WB, float bb, const _Float16* Afresh,
                              _Float16* dst, int cidx){
        i32x4 sf = make_srd(Afresh);
        f16x8 va[8], vb[8];
        f32x4 acc[4];
        #pragma unroll
        for (int rf = 0; rf < 4; ++rf){ acc[rf][0]=bb; acc[rf][1]=bb; acc[rf][2]=bb; acc[rf][3]=bb; }
        stage_rows8(sf, 0, va);
        khalf(buf1, WB+16, 0, 4, acc);
        stage_rows8(sf, 1, vb);
        khalf(buf1, WB+16, 4, 10, acc);
        write_rows8(buf0, 0, va);
        khalf(buf1, WB+16, 10, 16, acc);
        write_rows8(buf0, 1, vb);
        __syncthreads();                 // buf0 writes visible to all waves
        khalf(buf0, WB, 0, 16, acc);
        elementwise(acc, dst, cidx);
    };

    // encoder form: stages buf1 (avail) inline, then pipelines the fresh half.
    auto layer_step_enc = [&](const f16x8* WB, float bb, const _Float16* Afresh,
                              const _Float16* Aavail, _Float16* dst, int cidx){
        i32x4 sa = make_srd(Aavail);
        i32x4 sf = make_srd(Afresh);
        f16x8 va[8], vb[8];
        stage_rows8(sa, 0, va);
        stage_rows8(sa, 1, vb);
        write_rows8(buf1, 0, va);
        write_rows8(buf1, 1, vb);
        stage_rows8(sf, 0, va);
        __syncthreads();                 // buf1 ready
        f32x4 acc[4];
        #pragma unroll
        for (int rf = 0; rf < 4; ++rf){ acc[rf][0]=bb; acc[rf][1]=bb; acc[rf][2]=bb; acc[rf][3]=bb; }
        khalf(buf1, WB+16, 0, 6, acc);
        stage_rows8(sf, 1, vb);
        khalf(buf1, WB+16, 6, 16, acc);
        write_rows8(buf0, 0, va);
        write_rows8(buf0, 1, vb);
        __syncthreads();                 // buf0 ready
        khalf(buf0, WB, 0, 16, acc);
        elementwise(acc, dst, cidx);
    };

    auto gen_x = [&](int t, _Float16* xd){
        #pragma unroll
        for (int e = 0; e < 4; ++e){
            int idx = e*256 + tid;
            int row = r0 + jt*2 + (idx >> 9);
            int col = idx & 511;
            const float* tr = traj + ((size_t)row*TTRAJ + t)*3;
            const float* wv = encW + col*3;
            float v = encB[col] + tr[0]*wv[0] + tr[1]*wv[1] + tr[2]*wv[2];
            xd[(size_t)row*512 + col] = (_Float16)(v >= 0.f ? v : pa*v);
        }
    };

    auto emb_step = [&](int d, const _Float16* h1prev){
        f32x4 acc = {0.f,0.f,0.f,0.f};
        if (d > 0){
            i32x4 sh = make_srd(h1prev);
            const int vb = (r0 + w*16 + m)*1024 + q*16;
            const _Float16* bp = Mf + ((size_t)(j0 + m))*512 + q*8;
            // batch all 16 sc0 loads before the serially-dependent MFMA chain
            f16x8 hv0[8], hv1[8];
            #pragma unroll
            for (int i = 0; i < 8; ++i) hv0[i] = ldA(sh, vb + i*64);
            #pragma unroll
            for (int i = 0; i < 8; ++i) hv1[i] = ldA(sh, vb + (8+i)*64);
            #pragma unroll
            for (int i = 0; i < 8; ++i)
                acc = __builtin_amdgcn_mfma_f32_16x16x32_f16(
                    hv0[i], *(const f16x8*)(bp + i*32), acc, 0,0,0);
            #pragma unroll
            for (int i = 0; i < 8; ++i)
                acc = __builtin_amdgcn_mfma_f32_16x16x32_f16(
                    hv1[i], *(const f16x8*)(bp + (8+i)*32), acc, 0,0,0);
        }
        const int col = j0 + m;
        const float ts = (float)(d+1) * (1.0f/120.0f);
        const float add = ts * w712[col] + ((d > 0) ? constj[col] : 0.f);
        #pragma unroll
        for (int r = 0; r < 4; ++r){
            int row = r0 + w*16 + q*4 + r;
            float v = acc[r] + cond[(size_t)row*512 + col] + add;
            xdec[(size_t)row*512 + col] = (_Float16)(v >= 0.f ? v : pa*v);
        }
    };

    // out tiles stay inside group rows: block jt<20 computes tile (jt/5, jt%5).
    // K=16 kc split across all 4 waves (4 each), partials reduced via gx.
    // ALL blocks must call (contains block-wide __syncthreads).
    auto out_step = [&](int dprev, const _Float16* h1v){
        if (jt < 20){
            int b0 = r0 + (jt/5)*16;
            int f0 = (jt%5)*16;
            f32x4 acc = {0.f,0.f,0.f,0.f};
            i32x4 sh = make_srd(h1v);
            const int vb = (b0 + m)*1024 + q*16;
            const _Float16* bp = outWf + ((size_t)(f0 + m))*512 + q*8;
            f16x8 hv[4];
            #pragma unroll
            for (int i = 0; i < 4; ++i) hv[i] = ldA(sh, vb + (w*4+i)*64);
            #pragma unroll
            for (int i = 0; i < 4; ++i)
                acc = __builtin_amdgcn_mfma_f32_16x16x32_f16(
                    hv[i], *(const f16x8*)(bp + (w*4+i)*32), acc, 0,0,0);
            #pragma unroll
            for (int r = 0; r < 4; ++r) gx[w][q*4+r][m] = acc[r];
        }
        __syncthreads();
        if (jt < 20 && w == 0){
            int b0 = r0 + (jt/5)*16;
            int f  = (jt%5)*16 + m;
            if (f < FF){
                float ob = outB[f];
                #pragma unroll
                for (int r = 0; r < 4; ++r){
                    int b = b0 + q*4 + r;
                    int rr = q*4 + r;
                    dout[((size_t)b*TOUT + dprev)*FF + f] =
                        gx[0][rr][m] + gx[1][rr][m] + gx[2][rr][m] + gx[3][rr][m] + ob;
                }
            }
        }
    };

    // ---- load encoder weights into registers ----
    load_wb(wcat + 0*WSZE, wcat + 1*WSZE);
    float bb0 = biasC[0*GG + w*512 + j0 + m];
    float bb1 = biasC[1*GG + w*512 + j0 + m];
    __syncthreads();

    gen_x(0, xping);
    gbar();

    // ---- encoder: segment t pairs L1(t-1) with L0(t): 1 barrier per step ----
    // layer args: (WB, bias, A_fresh = x-input just gbar'd, A_avail = own
    // recurrent h from the previous iteration, dst, cell idx)
    for (int t = 0; t <= 120; ++t){
        int cur = t & 1, prv = cur ^ 1;
        if (t >= 1)
            layer_step_enc(WB1, bb1, h0p + (size_t)prv*BH, h1p + (size_t)cur*BH,
                           h1p + (size_t)prv*BH, 1);
        if (t < 120){
            layer_step_enc(WB0, bb0, xping + (size_t)cur*BH, h0p + (size_t)prv*BH,
                           h0p + (size_t)cur*BH, 0);
            if (t + 1 < 120) gen_x(t + 1, xping + (size_t)prv*BH);
        }
        gbar();
    }

    // ---- decoder: reload registers with decoder weights ----
    load_wb(wcat + 2*WSZE, wcat + 3*WSZE);
    bb0 = biasC[2*GG + w*512 + j0 + m];
    bb1 = biasC[3*GG + w*512 + j0 + m];

    for (int d = 0; d < 120; ++d){
        int cur = d & 1, prv = cur ^ 1;
        emb_step(d, h1p + (size_t)prv*BH);
        if (d > 0) out_step(d - 1, h1p + (size_t)prv*BH);
        stage_avail(h0p + (size_t)prv*BH);          // L0's recurrent h (2 epochs old)
        gbar();
        layer_step_dec(WB0, bb0, xdec, h0p + (size_t)cur*BH, 0);
        gbar_begin();
        stage_avail(h1p + (size_t)prv*BH);          // L1's recurrent h (2 epochs old)
        gbar_end();
        layer_step_dec(WB1, bb1, h0p + (size_t)cur*BH, h1p + (size_t)cur*BH, 1);
        gbar();
    }
    out_step(119, h1p + (size_t)1*BH);
}

extern "C" void kernel_launch(void* const* d_in, const int* in_sizes, int n_in,
                              void* d_out, int out_size, void* d_ws, size_t ws_size,
                              hipStream_t stream)
{
    (void)in_sizes; (void)n_in; (void)out_size; (void)ws_size;
    const float* label   = (const float*)d_in[1];
    const float* cemb    = (const float*)d_in[2];
    const float* traj    = (const float*)d_in[3];
    const float* encW    = (const float*)d_in[4];
    const float* encB    = (const float*)d_in[5];
    const float* prelu_a = (const float*)d_in[6];
    const float* embW    = (const float*)d_in[7];
    const float* embB    = (const float*)d_in[8];
    const float* outW    = (const float*)d_in[9];
    const float* outB    = (const float*)d_in[10];
    const float* encWih  = (const float*)d_in[11];
    const float* encWhh  = (const float*)d_in[12];
    const float* encbih  = (const float*)d_in[13];
    const float* encbhh  = (const float*)d_in[14];
    const float* decWih  = (const float*)d_in[15];
    const float* decWhh  = (const float*)d_in[16];
    const float* decbih  = (const float*)d_in[17];
    const float* decbhh  = (const float*)d_in[18];
    float* out = (float*)d_out;

    char* ws = (char*)d_ws;
    size_t off = 0;
    auto alloc = [&](size_t bytes)->char*{
        char* p = ws + off; off = (off + bytes + 255) & ~(size_t)255; return p;
    };
    _Float16* wcat  = (_Float16*)alloc(4*WSZE*2);
    _Float16* xping = (_Float16*)alloc(2*BH*2);
    _Float16* h0p   = (_Float16*)alloc(2*BH*2);
    _Float16* h1p   = (_Float16*)alloc(2*BH*2);
    _Float16* xdec  = (_Float16*)alloc(BH*2);
    float*    cond  = (float*)   alloc(BH*4);
    _Float16* Mf    = (_Float16*)alloc(512*512*2);
    _Float16* outWf = (_Float16*)alloc(80*512*2);
    float*    biasC = (float*)   alloc(4*GG*4);
    float*    w712  = (float*)   alloc(512*4);
    float*    constj= (float*)   alloc(512*4);
    unsigned* bar   = (unsigned*)alloc(8*32*32*4);   // 8 groups x 32 flags x 128B

    // zero h0p + h1p (contiguous 2MB) and barrier flags
    hipMemsetAsync(h0p, 0, 4*BH*2, stream);
    hipMemsetAsync(bar, 0, 8*32*32*4, stream);

    conv_wcat_kernel<<<2048, 256, 0, stream>>>(encWih,                 encWhh,                 wcat + 0*WSZE);
    conv_wcat_kernel<<<2048, 256, 0, stream>>>(encWih + (size_t)GG*HH, encWhh + (size_t)GG*HH, wcat + 1*WSZE);
    conv_wcat_kernel<<<2048, 256, 0, stream>>>(decWih,                 decWhh,                 wcat + 2*WSZE);
    conv_wcat_kernel<<<2048, 256, 0, stream>>>(decWih + (size_t)GG*HH, decWhh + (size_t)GG*HH, wcat + 3*WSZE);
    cond_kernel<<<BB, 256, 0, stream>>>(label, cemb, embW, embB, cond);
    mf_kernel<<<1024, 256, 0, stream>>>(embW, outW, Mf);
    prep_kernel<<<197, 256, 0, stream>>>(encbih, encbhh, decbih, decbhh, embW, outW, outB,
                                         biasC, w712, constj, outWf);

    persistent_kernel<<<256, 256, 0, stream>>>(
        wcat, biasC, traj, encW, encB, prelu_a, xping, h0p, h1p, xdec,
        cond, Mf, w712, constj, outWf, outB, out, bar);
}

// Round 7
// 4088.932 us; speedup vs baseline: 1.1318x; 1.1318x over previous
//
#include <hip/hip_runtime.h>
#include <math.h>

#define BB 512
#define HH 512
#define FF 72
#define NCC 10
#define EE 64
#define TTRAJ 120
#define TOUT 120
#define INWW 713
#define GG 2048
#define WSZE ((size_t)GG*1024)    // elements per converted weight matrix
#define BH  ((size_t)BB*HH)       // elements per activation buffer

typedef _Float16 f16x8 __attribute__((ext_vector_type(8)));
typedef float f32x4 __attribute__((ext_vector_type(4)));
typedef int i32x4 __attribute__((ext_vector_type(4)));

__device__ __forceinline__ float sigmoidf_(float x){ return 1.0f/(1.0f+__expf(-x)); }

// sc0 (L1-bypass) 16B load via raw buffer intrinsic (validated r5/r7): reads
// the XCD L2 directly where same-XCD producers' dirty activation lines live.
extern "C" __device__ f32x4 llvm_amdgcn_raw_buffer_load_v4f32(
    i32x4 rsrc, int voffset, int soffset, int cpol) __asm("llvm.amdgcn.raw.buffer.load.v4f32");

__device__ __forceinline__ i32x4 make_srd(const void* p){
    union { const void* p; unsigned long long u; } a; a.p = p;
    i32x4 r;
    r.x = (int)(a.u & 0xFFFFFFFFull);
    r.y = (int)(a.u >> 32);          // stride=0, base hi bits
    r.z = -1;                        // num_records = 0xFFFFFFFF (bounds off)
    r.w = 0x00020000;                // raw dword access
    return r;
}

__device__ __forceinline__ f16x8 ldA(i32x4 srd, int voff){
    f32x4 v = llvm_amdgcn_raw_buffer_load_v4f32(srd, voff, 0, 1);  // sc0
    union { f32x4 f; f16x8 h; } u; u.f = v; return u.h;
}

// Build fp16 Wcat[g*512+j][0:512]=Wih, [512:1024]=Whh
__global__ void conv_wcat_kernel(const float* __restrict__ ih,
                                 const float* __restrict__ hh,
                                 _Float16* __restrict__ dst)
{
    int idx = blockIdx.x*256 + threadIdx.x;   // 2048*256 quads
    int j  = idx >> 8;
    int k4 = (idx & 255) * 4;
    const float* src = (k4 < 512) ? (ih + (size_t)j*512 + k4)
                                  : (hh + (size_t)j*512 + (k4-512));
    float4 v = *(const float4*)src;
    _Float16* d = dst + (size_t)j*1024 + k4;
    d[0] = (_Float16)v.x; d[1] = (_Float16)v.y;
    d[2] = (_Float16)v.z; d[3] = (_Float16)v.w;
}

// cond_out[b*H+j] = emb_b[j] + sum_i (label outer cemb)[b,i]*emb_W[j][72+i]
__global__ void cond_kernel(const float* __restrict__ label,
                            const float* __restrict__ cemb,
                            const float* __restrict__ embW,
                            const float* __restrict__ embB,
                            float* __restrict__ cond_out)
{
    __shared__ float sl[NCC];
    __shared__ float se[EE];
    __shared__ float sc[NCC*EE];
    int b = blockIdx.x;
    int tid = threadIdx.x;
    if (tid < NCC) sl[tid] = label[b*NCC + tid];
    else if (tid >= 32 && tid < 32+EE) se[tid-32] = cemb[b*EE + (tid-32)];
    __syncthreads();
    for (int i = tid; i < NCC*EE; i += 256) sc[i] = sl[i>>6]*se[i&63];
    __syncthreads();
    for (int j = tid; j < HH; j += 256){
        const float* w = embW + (size_t)j*INWW + FF;
        float acc = embB[j];
        #pragma unroll 8
        for (int i = 0; i < NCC*EE; ++i) acc += sc[i]*w[i];
        cond_out[b*HH + j] = acc;
    }
}

// Mf[j][k] = sum_f embW[j][f]*outW[f][k]   (fp16 out)
__global__ void mf_kernel(const float* __restrict__ embW,
                          const float* __restrict__ outW,
                          _Float16* __restrict__ Mf)
{
    int idx = blockIdx.x*256 + threadIdx.x;   // 512*512
    int j = idx >> 9, k = idx & 511;
    const float* ew = embW + (size_t)j*INWW;
    float acc = 0.f;
    #pragma unroll 8
    for (int f = 0; f < FF; ++f) acc += ew[f] * outW[f*512 + k];
    Mf[idx] = (_Float16)acc;
}

// biasC[4][2048], w712[512], constj[512], outWf[80][512] (fp16, zero-padded)
__global__ void prep_kernel(const float* __restrict__ encbih, const float* __restrict__ encbhh,
                            const float* __restrict__ decbih, const float* __restrict__ decbhh,
                            const float* __restrict__ embW, const float* __restrict__ outW,
                            const float* __restrict__ outB,
                            float* __restrict__ biasC, float* __restrict__ w712,
                            float* __restrict__ constj, _Float16* __restrict__ outWf)
{
    int i = blockIdx.x*256 + threadIdx.x;
    if (i < 8192){
        int l = i >> 11, g = i & 2047;
        biasC[i] = (l < 2) ? encbih[l*GG+g] + encbhh[l*GG+g]
                           : decbih[(l-2)*GG+g] + decbhh[(l-2)*GG+g];
    } else if (i < 8704){
        int j = i - 8192;
        w712[j] = embW[(size_t)j*INWW + (INWW-1)];
    } else if (i < 9216){
        int j = i - 8704;
        float acc = 0.f;
        #pragma unroll 8
        for (int f = 0; f < FF; ++f) acc += embW[(size_t)j*INWW + f] * outB[f];
        constj[j] = acc;
    } else if (i < 9216 + 80*512){
        int ii = i - 9216;
        int f = ii >> 9, k = ii & 511;
        outWf[ii] = (f < FF) ? (_Float16)outW[f*512 + k] : (_Float16)0.f;
    }
}

// ---------------- persistent kernel (normal launch + flag group barriers) ----
// 256 blocks x 256 threads, 1 block/CU. rt = bid&7 (XCD-local group of 32 blocks),
// jt = bid>>3. Block owns rows rt*64..+63, h-cols jt*16..+15. Wave w = gate w.
__global__ __launch_bounds__(256, 1)
void persistent_kernel(const _Float16* __restrict__ wcat, const float* __restrict__ biasC,
                       const float* __restrict__ traj, const float* __restrict__ encW,
                       const float* __restrict__ encB, const float* __restrict__ prelu_a,
                       _Float16* __restrict__ xping, _Float16* __restrict__ h0p,
                       _Float16* __restrict__ h1p, _Float16* __restrict__ xdec,
                       const float* __restrict__ cond, const _Float16* __restrict__ Mf,
                       const float* __restrict__ w712, const float* __restrict__ constj,
                       const _Float16* __restrict__ outWf, const float* __restrict__ outB,
                       float* __restrict__ dout, unsigned* __restrict__ bar)
{
    // smem layout:
    //   [0      ..  65536)  buf0[64][512] fp16 — FRESH A-half, XOR-swizzled:
    //                       buf[row][y] = A[row][y ^ ((row&7)<<4)]
    //   [65536  .. 131072)  buf1[64][512] fp16 — AVAIL A-half (recurrent h)
    //   [131072 .. 148480)  gx[4][64][17]  f32
    //   [148480 .. 157184)  cst[2][64][17] f32 — persistent cell state
    __shared__ __align__(16) char smem[157184];
    char* buf0 = smem;
    char* buf1 = smem + 65536;
    float (*gx)[64][17]  = (float (*)[64][17])(smem + 131072);
    float (*cst)[64][17] = (float (*)[64][17])(smem + 148480);

    const int tid = threadIdx.x;
    const int w    = tid >> 6;       // gate / weight-group
    const int lane = tid & 63;
    const int m    = lane & 15;
    const int q    = lane >> 4;
    const int bid  = blockIdx.x;
    const int rt   = bid & 7;        // group id (XCD-local under %8 round-robin)
    const int jt   = bid >> 3;       // 0..31
    const int r0   = rt * 64;
    const int j0   = jt * 16;
    const float pa = prelu_a[0];
    unsigned* fl = bar + rt*32*32;   // 32 flags, 128B apart
    unsigned seq = 0;

    // Round-7 barrier protocol, verbatim semantics (monotone seq, volatile
    // store, wave-0 volatile poll, no fences/RMW, 128B-apart flags). Split
    // begin/end so stale-data staging can be overlapped into the wait window.
    auto gbar_begin = [&](){
        ++seq;
        __syncthreads();
        if (tid == 0)
            *(volatile unsigned*)(fl + jt*32) = seq;
    };
    auto gbar_end = [&](){
        if (tid < 64){
            long long t0 = clock64();
            for(;;){
                unsigned v = (tid < 32) ? *(volatile unsigned*)(fl + tid*32) : seq;
                if (__ballot((int)(seq - v) > 0) == 0ULL) break;
                __builtin_amdgcn_s_sleep(1);
                if (clock64() - t0 > 40000000LL) break;   // bail: wrong answer beats hang
            }
        }
        __syncthreads();
    };
    auto gbar = [&](){ gbar_begin(); gbar_end(); };

    for (int i = tid; i < 2*64*17; i += 256) ((float*)(smem + 148480))[i] = 0.f;

    f16x8 WB0[32], WB1[32];
    auto load_wb = [&](const _Float16* base0, const _Float16* base1){
        const _Float16* p0 = base0 + ((size_t)(w*512 + j0 + m))*1024 + q*8;
        const _Float16* p1 = base1 + ((size_t)(w*512 + j0 + m))*1024 + q*8;
        #pragma unroll
        for (int kc = 0; kc < 32; ++kc){
            WB0[kc] = *(const f16x8*)(p0 + kc*32);
            WB1[kc] = *(const f16x8*)(p1 + kc*32);
        }
    };

    // wave w owns rows {(g*8+i)*4+w}; per row, lanes read 1KB contiguous (sc0,
    // coalesced) and write 1KB to one LDS row (wave-uniform row, swizzled cols).
    auto stage_rows8 = [&](i32x4 s, int g, f16x8* v){
        #pragma unroll
        for (int i = 0; i < 8; ++i)
            v[i] = ldA(s, (r0 + (g*8 + i)*4 + w)*1024 + lane*16);
    };
    auto write_rows8 = [&](char* buf, int g, f16x8* v){
        #pragma unroll
        for (int i = 0; i < 8; ++i){
            const int row = (g*8 + i)*4 + w;
            *(f16x8*)(buf + row*1024 + ((lane*16) ^ ((row&7)<<4))) = v[i];
        }
    };
    // stage the avail (recurrent) half into buf1: used inside barrier windows /
    // emb segments; completion guaranteed by the next __syncthreads.
    auto stage_avail = [&](const _Float16* A){
        i32x4 s = make_srd(A);
        f16x8 va[8], vb[8];
        stage_rows8(s, 0, va);
        stage_rows8(s, 1, vb);
        write_rows8(buf1, 0, va);
        write_rows8(buf1, 1, vb);
    };

    // per-thread swizzled base: row m, col bytes q*16, XOR (m&7)<<4.
    // kc*64 folds via XOR (disjoint bits within the 1024B row); rf*16384
    // adds 16 rows (row&7 invariant -> same swizzle).
    const int at = m*1024 + ((q*16) ^ ((m&7)<<4));

    auto khalf = [&](const char* ab, const f16x8* WBh, int c0, int c1, f32x4* acc){
        #pragma unroll
        for (int kc = c0; kc < c1; ++kc){
            const int ko = at ^ (kc*64);
            #pragma unroll
            for (int rf = 0; rf < 4; ++rf){
                f16x8 av = *(const f16x8*)(ab + (ko + rf*16384));
                acc[rf] = __builtin_amdgcn_mfma_f32_16x16x32_f16(av, WBh[kc], acc[rf], 0,0,0);
            }
        }
    };

    auto elementwise = [&](f32x4* acc, _Float16* dst, int cidx){
        #pragma unroll
        for (int rf = 0; rf < 4; ++rf)
            #pragma unroll
            for (int r = 0; r < 4; ++r)
                gx[w][rf*16 + q*4 + r][m] = acc[rf][r];
        __syncthreads();
        #pragma unroll
        for (int r = 0; r < 4; ++r){
            int row = w*16 + q*4 + r;
            float ig = sigmoidf_(gx[0][row][m]);
            float fg = sigmoidf_(gx[1][row][m]);
            float gv = tanhf(gx[2][row][m]);
            float og = sigmoidf_(gx[3][row][m]);
            float cp = cst[cidx][row][m];
            float cn = fg*cp + ig*gv;
            cst[cidx][row][m] = cn;
            dst[((size_t)(r0 + row))*512 + j0 + m] = (_Float16)(og*tanhf(cn));
        }
    };

    // decoder form: buf1 already holds the avail half (staged in a barrier
    // window). Fresh-half loads are interleaved with avail-half MFMAs.
    auto layer_step_dec = [&](const f16x8* WB, float bb, const _Float16* Afresh,
                              _Float16* dst, int cidx){
        i32x4 sf = make_srd(Afresh);
        f16x8 va[8], vb[8];
        f32x4 acc[4];
        #pragma unroll
        for (int rf = 0; rf < 4; ++rf){ acc[rf][0]=bb; acc[rf][1]=bb; acc[rf][2]=bb; acc[rf][3]=bb; }
        stage_rows8(sf, 0, va);
        khalf(buf1, WB+16, 0, 4, acc);
        stage_rows8(sf, 1, vb);
        khalf(buf1, WB+16, 4, 10, acc);
        write_rows8(buf0, 0, va);
        khalf(buf1, WB+16, 10, 16, acc);
        write_rows8(buf0, 1, vb);
        __syncthreads();                 // buf0 writes visible to all waves
        khalf(buf0, WB, 0, 16, acc);
        elementwise(acc, dst, cidx);
    };

    // encoder form: stages buf1 (avail) inline, then pipelines the fresh half.
    auto layer_step_enc = [&](const f16x8* WB, float bb, const _Float16* Afresh,
                              const _Float16* Aavail, _Float16* dst, int cidx){
        i32x4 sa = make_srd(Aavail);
        i32x4 sf = make_srd(Afresh);
        f16x8 va[8], vb[8];
        stage_rows8(sa, 0, va);
        stage_rows8(sa, 1, vb);
        write_rows8(buf1, 0, va);
        write_rows8(buf1, 1, vb);
        stage_rows8(sf, 0, va);
        __syncthreads();                 // buf1 ready
        f32x4 acc[4];
        #pragma unroll
        for (int rf = 0; rf < 4; ++rf){ acc[rf][0]=bb; acc[rf][1]=bb; acc[rf][2]=bb; acc[rf][3]=bb; }
        khalf(buf1, WB+16, 0, 6, acc);
        stage_rows8(sf, 1, vb);
        khalf(buf1, WB+16, 6, 16, acc);
        write_rows8(buf0, 0, va);
        write_rows8(buf0, 1, vb);
        __syncthreads();                 // buf0 ready
        khalf(buf0, WB, 0, 16, acc);
        elementwise(acc, dst, cidx);
    };

    auto gen_x = [&](int t, _Float16* xd){
        #pragma unroll
        for (int e = 0; e < 4; ++e){
            int idx = e*256 + tid;
            int row = r0 + jt*2 + (idx >> 9);
            int col = idx & 511;
            const float* tr = traj + ((size_t)row*TTRAJ + t)*3;
            const float* wv = encW + col*3;
            float v = encB[col] + tr[0]*wv[0] + tr[1]*wv[1] + tr[2]*wv[2];
            xd[(size_t)row*512 + col] = (_Float16)(v >= 0.f ? v : pa*v);
        }
    };

    auto emb_step = [&](int d, const _Float16* h1prev){
        f32x4 acc = {0.f,0.f,0.f,0.f};
        if (d > 0){
            i32x4 sh = make_srd(h1prev);
            const int vb = (r0 + w*16 + m)*1024 + q*16;
            const _Float16* bp = Mf + ((size_t)(j0 + m))*512 + q*8;
            // batch all 16 sc0 loads before the serially-dependent MFMA chain
            f16x8 hv0[8], hv1[8];
            #pragma unroll
            for (int i = 0; i < 8; ++i) hv0[i] = ldA(sh, vb + i*64);
            #pragma unroll
            for (int i = 0; i < 8; ++i) hv1[i] = ldA(sh, vb + (8+i)*64);
            #pragma unroll
            for (int i = 0; i < 8; ++i)
                acc = __builtin_amdgcn_mfma_f32_16x16x32_f16(
                    hv0[i], *(const f16x8*)(bp + i*32), acc, 0,0,0);
            #pragma unroll
            for (int i = 0; i < 8; ++i)
                acc = __builtin_amdgcn_mfma_f32_16x16x32_f16(
                    hv1[i], *(const f16x8*)(bp + (8+i)*32), acc, 0,0,0);
        }
        const int col = j0 + m;
        const float ts = (float)(d+1) * (1.0f/120.0f);
        const float add = ts * w712[col] + ((d > 0) ? constj[col] : 0.f);
        #pragma unroll
        for (int r = 0; r < 4; ++r){
            int row = r0 + w*16 + q*4 + r;
            float v = acc[r] + cond[(size_t)row*512 + col] + add;
            xdec[(size_t)row*512 + col] = (_Float16)(v >= 0.f ? v : pa*v);
        }
    };

    // out tiles stay inside group rows: block jt<20, wave 0: tile (jt/5, jt%5)
    auto out_step = [&](int dprev, const _Float16* h1v){
        if (jt >= 20 || w != 0) return;
        int b0 = r0 + (jt/5)*16;
        int f0 = (jt%5)*16;
        f32x4 acc = {0.f,0.f,0.f,0.f};
        i32x4 sh = make_srd(h1v);
        const int vb = (b0 + m)*1024 + q*16;
        const _Float16* bp = outWf + ((size_t)(f0 + m))*512 + q*8;
        f16x8 hv0[8], hv1[8];
        #pragma unroll
        for (int i = 0; i < 8; ++i) hv0[i] = ldA(sh, vb + i*64);
        #pragma unroll
        for (int i = 0; i < 8; ++i) hv1[i] = ldA(sh, vb + (8+i)*64);
        #pragma unroll
        for (int i = 0; i < 8; ++i)
            acc = __builtin_amdgcn_mfma_f32_16x16x32_f16(
                hv0[i], *(const f16x8*)(bp + i*32), acc, 0,0,0);
        #pragma unroll
        for (int i = 0; i < 8; ++i)
            acc = __builtin_amdgcn_mfma_f32_16x16x32_f16(
                hv1[i], *(const f16x8*)(bp + (8+i)*32), acc, 0,0,0);
        int f = f0 + m;
        if (f < FF){
            float ob = outB[f];
            #pragma unroll
            for (int r = 0; r < 4; ++r){
                int b = b0 + q*4 + r;
                dout[((size_t)b*TOUT + dprev)*FF + f] = acc[r] + ob;
            }
        }
    };

    // ---- load encoder weights into registers ----
    load_wb(wcat + 0*WSZE, wcat + 1*WSZE);
    float bb0 = biasC[0*GG + w*512 + j0 + m];
    float bb1 = biasC[1*GG + w*512 + j0 + m];
    __syncthreads();

    gen_x(0, xping);
    gbar();

    // ---- encoder: segment t pairs L1(t-1) with L0(t): 1 barrier per step ----
    // layer args: (WB, bias, A_fresh = x-input just gbar'd, A_avail = own
    // recurrent h from the previous iteration, dst, cell idx)
    for (int t = 0; t <= 120; ++t){
        int cur = t & 1, prv = cur ^ 1;
        if (t >= 1)
            layer_step_enc(WB1, bb1, h0p + (size_t)prv*BH, h1p + (size_t)cur*BH,
                           h1p + (size_t)prv*BH, 1);
        if (t < 120){
            layer_step_enc(WB0, bb0, xping + (size_t)cur*BH, h0p + (size_t)prv*BH,
                           h0p + (size_t)cur*BH, 0);
            if (t + 1 < 120) gen_x(t + 1, xping + (size_t)prv*BH);
        }
        gbar();
    }

    // ---- decoder: reload registers with decoder weights ----
    load_wb(wcat + 2*WSZE, wcat + 3*WSZE);
    bb0 = biasC[2*GG + w*512 + j0 + m];
    bb1 = biasC[3*GG + w*512 + j0 + m];

    for (int d = 0; d < 120; ++d){
        int cur = d & 1, prv = cur ^ 1;
        emb_step(d, h1p + (size_t)prv*BH);
        if (d > 0) out_step(d - 1, h1p + (size_t)prv*BH);
        stage_avail(h0p + (size_t)prv*BH);          // L0's recurrent h (2 epochs old)
        gbar();
        layer_step_dec(WB0, bb0, xdec, h0p + (size_t)cur*BH, 0);
        gbar_begin();
        stage_avail(h1p + (size_t)prv*BH);          // L1's recurrent h (2 epochs old)
        gbar_end();
        layer_step_dec(WB1, bb1, h0p + (size_t)cur*BH, h1p + (size_t)cur*BH, 1);
        gbar();
    }
    out_step(119, h1p + (size_t)1*BH);
}

extern "C" void kernel_launch(void* const* d_in, const int* in_sizes, int n_in,
                              void* d_out, int out_size, void* d_ws, size_t ws_size,
                              hipStream_t stream)
{
    (void)in_sizes; (void)n_in; (void)out_size; (void)ws_size;
    const float* label   = (const float*)d_in[1];
    const float* cemb    = (const float*)d_in[2];
    const float* traj    = (const float*)d_in[3];
    const float* encW    = (const float*)d_in[4];
    const float* encB    = (const float*)d_in[5];
    const float* prelu_a = (const float*)d_in[6];
    const float* embW    = (const float*)d_in[7];
    const float* embB    = (const float*)d_in[8];
    const float* outW    = (const float*)d_in[9];
    const float* outB    = (const float*)d_in[10];
    const float* encWih  = (const float*)d_in[11];
    const float* encWhh  = (const float*)d_in[12];
    const float* encbih  = (const float*)d_in[13];
    const float* encbhh  = (const float*)d_in[14];
    const float* decWih  = (const float*)d_in[15];
    const float* decWhh  = (const float*)d_in[16];
    const float* decbih  = (const float*)d_in[17];
    const float* decbhh  = (const float*)d_in[18];
    float* out = (float*)d_out;

    char* ws = (char*)d_ws;
    size_t off = 0;
    auto alloc = [&](size_t bytes)->char*{
        char* p = ws + off; off = (off + bytes + 255) & ~(size_t)255; return p;
    };
    _Float16* wcat  = (_Float16*)alloc(4*WSZE*2);
    _Float16* xping = (_Float16*)alloc(2*BH*2);
    _Float16* h0p   = (_Float16*)alloc(2*BH*2);
    _Float16* h1p   = (_Float16*)alloc(2*BH*2);
    _Float16* xdec  = (_Float16*)alloc(BH*2);
    float*    cond  = (float*)   alloc(BH*4);
    _Float16* Mf    = (_Float16*)alloc(512*512*2);
    _Float16* outWf = (_Float16*)alloc(80*512*2);
    float*    biasC = (float*)   alloc(4*GG*4);
    float*    w712  = (float*)   alloc(512*4);
    float*    constj= (float*)   alloc(512*4);
    unsigned* bar   = (unsigned*)alloc(8*32*32*4);   // 8 groups x 32 flags x 128B

    // zero h0p + h1p (contiguous 2MB) and barrier flags
    hipMemsetAsync(h0p, 0, 4*BH*2, stream);
    hipMemsetAsync(bar, 0, 8*32*32*4, stream);

    conv_wcat_kernel<<<2048, 256, 0, stream>>>(encWih,                 encWhh,                 wcat + 0*WSZE);
    conv_wcat_kernel<<<2048, 256, 0, stream>>>(encWih + (size_t)GG*HH, encWhh + (size_t)GG*HH, wcat + 1*WSZE);
    conv_wcat_kernel<<<2048, 256, 0, stream>>>(decWih,                 decWhh,                 wcat + 2*WSZE);
    conv_wcat_kernel<<<2048, 256, 0, stream>>>(decWih + (size_t)GG*HH, decWhh + (size_t)GG*HH, wcat + 3*WSZE);
    cond_kernel<<<BB, 256, 0, stream>>>(label, cemb, embW, embB, cond);
    mf_kernel<<<1024, 256, 0, stream>>>(embW, outW, Mf);
    prep_kernel<<<197, 256, 0, stream>>>(encbih, encbhh, decbih, decbhh, embW, outW, outB,
                                         biasC, w712, constj, outWf);

    persistent_kernel<<<256, 256, 0, stream>>>(
        wcat, biasC, traj, encW, encB, prelu_a, xping, h0p, h1p, xdec,
        cond, Mf, w712, constj, outWf, outB, out, bar);
}